// Round 10
// baseline (109.273 us; speedup 1.0000x reference)
//
#include <hip/hip_runtime.h>
#include <hip/hip_cooperative_groups.h>
#include <stdint.h>

namespace cg = cooperative_groups;

// SCLinear: out = sc_mat_mac_p(x, W, b, lut, 32)  (forward value of
// lin + stop_grad(p - lin) is exactly p).
// lut[i][j] == floor(i*j/32)  =>  sgn*lut[|a|,|b|] == trunc-toward-zero(a*b/32).
// Exact small-integer arithmetic; no lut memory needed.
//
// R23: COOPERATIVE GRID SYNC (one dispatch, non-redundant reduction).
// History: R13 publish/poll (sc0/sc1) = 74.7us total (~18us cross-XCD
// visibility stall). R14 two-kernel = 76.8 (second dispatch ~11us).
// R15/R22 redundant per-block scan = 94.3/87.8 (scan ~43/~37us; staggering
// helped only 14% -> slice-camping refuted as dominant mechanism; the
// 200MB redundant scan has a ~10us floor regardless).
// This round: the untried mechanism. hipLaunchCooperativeKernel +
// grid.sync() gives a device-scope release/acquire barrier (correct
// cross-XCD visibility, which R13's relaxed uncached loads lacked):
//   phase A: block B scans ONLY its 1/256 slice of {x,W,b} (3KB),
//            block-reduces, writes partial pair to wsp[2B..2B+1].
//   grid.sync()
//   phase B: every block reads the 256 pairs (512B), reduces -> exact
//            (e2,e1); quantize 2 x-rows into LDS; integer MAC (unchanged
//            verified math); write out.
// No speculation, no fixup, no poll, no redundant scan.
// Co-residency: 256 blocks x 512 thr = 8 waves/CU on 256 CUs -- fits.

#define MROWS 512
#define KDIM  256
#define OCOLS 256
#define NTHR  512
#define RPB   2                 // rows per block
#define NBLK  (MROWS / RPB)     // 256
#define NWAVE (NTHR / 64)

__device__ __forceinline__ void get_scales(float amax, float dmax, int& e2, int& e1) {
    if (amax == 0.0f) amax = 1.0f;
    if (dmax == 0.0f) dmax = 1.0f;
    float q2 = 32.0f / amax;
    float q1 = 32.0f / dmax;
    int f2 = (q2 >= 1073741824.0f) ? 0x40000000 : (int)floorf(q2);
    int f1 = (q1 >= 1073741824.0f) ? 0x40000000 : (int)floorf(q1);
    if (f2 < 1) f2 = 1;
    if (f1 < 1) f1 = 1;
    e2 = 31 - __clz(f2);
    e1 = 31 - __clz(f1);
}

__device__ __forceinline__ float max4(float4 v) {
    return fmaxf(fmaxf(fabsf(v.x), fabsf(v.y)), fmaxf(fabsf(v.z), fabsf(v.w)));
}

__global__ __launch_bounds__(NTHR)
void k_coop(unsigned int* __restrict__ wsp, const float* __restrict__ x,
            const float* __restrict__ W, const float* __restrict__ b,
            float* __restrict__ out) {
    __shared__ unsigned int a_sh[RPB][KDIM / 4];
    __shared__ float sm[2 * NWAVE];
    __shared__ int s_e[2];

    const int tid  = threadIdx.x;
    const int wave = tid >> 6;
    const int bx   = blockIdx.x;
    const int m0   = bx * RPB;

    const float4* xf = (const float4*)x;     // 32768 float4
    const float4* wf = (const float4*)W;     // 16384 float4

    // ---- phase A: non-redundant slice scan (3KB per block) ----
    float va = 0.0f, vd = 0.0f;
    if (tid < 128) va = max4(xf[bx * 128 + tid]);          // x: 128 f4/block
    if (tid < 64)  vd = max4(wf[bx * 64 + tid]);           // W: 64 f4/block
    if (bx == 0 && tid < 64)                               // b: 64 f4 total
        vd = fmaxf(vd, max4(((const float4*)b)[tid]));
    #pragma unroll
    for (int s = 32; s >= 1; s >>= 1) {
        va = fmaxf(va, __shfl_xor(va, s, 64));
        vd = fmaxf(vd, __shfl_xor(vd, s, 64));
    }
    if ((tid & 63) == 0) { sm[2 * wave] = va; sm[2 * wave + 1] = vd; }
    __syncthreads();
    if (tid == 0) {
        float a = sm[0], d = sm[1];
        #pragma unroll
        for (int i = 1; i < NWAVE; ++i) {
            a = fmaxf(a, sm[2 * i]);
            d = fmaxf(d, sm[2 * i + 1]);
        }
        wsp[2 * bx]     = __float_as_uint(a);
        wsp[2 * bx + 1] = __float_as_uint(d);
    }

    // ---- grid-wide barrier: device-scope release/acquire ----
    cg::this_grid().sync();

    // ---- phase B: reduce the 256 partial pairs (512B) ----
    float pa = 0.0f, pd = 0.0f;
    if (tid < 128) {                         // 128 uint4 = 256 pairs
        uint4 u = ((const uint4*)wsp)[tid];
        pa = fmaxf(__uint_as_float(u.x), __uint_as_float(u.z));
        pd = fmaxf(__uint_as_float(u.y), __uint_as_float(u.w));
    }
    #pragma unroll
    for (int s = 32; s >= 1; s >>= 1) {
        pa = fmaxf(pa, __shfl_xor(pa, s, 64));
        pd = fmaxf(pd, __shfl_xor(pd, s, 64));
    }
    if ((tid & 63) == 0) { sm[2 * wave] = pa; sm[2 * wave + 1] = pd; }
    __syncthreads();
    if (tid == 0) {
        float a = sm[0], d = sm[1];
        #pragma unroll
        for (int i = 1; i < NWAVE; ++i) {
            a = fmaxf(a, sm[2 * i]);
            d = fmaxf(d, sm[2 * i + 1]);
        }
        int e2, e1;
        get_scales(a, d, e2, e1);
        s_e[0] = e2; s_e[1] = e1;
    }
    __syncthreads();

    const int e2 = s_e[0];
    const int e1 = s_e[1];
    const float sn2f = (float)(1 << e2);
    const float sn1f = (float)(1 << e1);

    // ---- quantize the block's RPB x-rows into LDS (packed int8) ----
    if (tid < RPB * (KDIM / 4)) {            // 128 threads
        const int r = tid >> 6;
        const int o = tid & 63;
        float4 xv = xf[(size_t)(m0 + r) * (KDIM / 4) + o];
        int a0 = (int)(xv.x * sn2f) & 0xFF;
        int a1 = (int)(xv.y * sn2f) & 0xFF;
        int a2 = (int)(xv.z * sn2f) & 0xFF;
        int a3 = (int)(xv.w * sn2f) & 0xFF;
        a_sh[r][o] = (unsigned int)(a0 | (a1 << 8) | (a2 << 16) | (a3 << 24));
    }
    __syncthreads();

    // ---- integer MAC, thread (r,o) -> out[m0+r][o] ----
    const int o = tid & (OCOLS - 1);
    const int r = tid >> 8;                  // 0 or 1
    const float4* wrow = (const float4*)(W + (size_t)o * KDIM);
    const unsigned int* arow = a_sh[r];
    int sum = 0;
    #pragma unroll 8
    for (int kk = 0; kk < KDIM / 4; ++kk) {
        float4 wv = wrow[kk];
        unsigned int ap = arow[kk];
        float wfv[4] = {wv.x, wv.y, wv.z, wv.w};
        #pragma unroll
        for (int j = 0; j < 4; ++j) {
            int bv = (int)(wfv[j] * sn1f);
            int av = ((int)(ap << (24 - 8 * j))) >> 24;   // sign-extended byte j
            int s  = av * bv;
            sum += (s + ((s >> 31) & 31)) >> 5;           // == sgn*lut[|av|,|bv|]
        }
    }

    const int cc = (int)(b[o] * sn1f);
    const int d  = ((sum + ((sum >> 31) & ((1 << e2) - 1))) >> e2) + cc;
    out[(size_t)(m0 + r) * OCOLS + o] = (float)d * (1.0f / sn1f);
}

extern "C" void kernel_launch(void* const* d_in, const int* in_sizes, int n_in,
                              void* d_out, int out_size, void* d_ws, size_t ws_size,
                              hipStream_t stream) {
    const float* x = (const float*)d_in[0];
    const float* W = (const float*)d_in[1];
    const float* b = (const float*)d_in[2];
    // d_in[3] (lut) unused: lut[i][j] == floor(i*j/32), computed in-ALU.
    float* out = (float*)d_out;
    unsigned int* wsp = (unsigned int*)d_ws;   // 512 B of partial max pairs

    void* args[] = { (void*)&wsp, (void*)&x, (void*)&W, (void*)&b, (void*)&out };
    hipLaunchCooperativeKernel((const void*)k_coop, dim3(NBLK), dim3(NTHR),
                               args, 0, stream);
}

// Round 12
// 75.362 us; speedup vs baseline: 1.4500x; 1.4500x over previous
//
#include <hip/hip_runtime.h>
#include <stdint.h>

// SCLinear: out = sc_mat_mac_p(x, W, b, lut, 32)  (forward value of
// lin + stop_grad(p - lin) is exactly p).
// lut[i][j] == floor(i*j/32)  =>  sgn*lut[|a|,|b|] == trunc-toward-zero(a*b/32).
// Exact small-integer arithmetic; no lut memory needed.
//
// R25 == R24 resubmitted verbatim (R24 died in broker acquisition,
// kernel never ran).
//
// R24: R13's publish/poll redesigned as PUBLISH-EARLY / CONSUME-LATE,
// with dmax made COMMUNICATION-FREE.
// Measured history: R13 publish/poll 74.7 (18us visibility stall);
// R14 2-kernel 76.8 (dispatch ~11us); R15/R22 redundant scan 94/88;
// R23 cooperative grid.sync 109 (coop dispatch ~35us overhead). So:
// single plain dispatch + handshake, but restructured:
//  * dmax: every block already reads ALL of W (MAC) and ALL of b ->
//    fold max|W| into the MAC loop + |b[o]| => exact global dmax
//    locally, zero communication.
//  * amax: each block's 2 x-rows are loaded for quantization anyway;
//    their max is published at t~1.5us (one dword per block, 256 total)
//    and polled only AFTER the ~6us speculative MAC -> propagation
//    fully hidden.
//  * poll = one uncached dwordx4 per lane of wave 0 (256 dwords).
//  * speculative quant+MAC with guess (e2,e1)=(5,5) (true for bench
//    data); block-uniform exact fixup for arbitrary inputs.
// RPB=2: 256 blocks x 512 thr = 1 block/CU (co-residency for the poll
// is safe), and halves aggregate W re-reads vs R13 (64MB).
// wsp[bx] = block bx's x-rowpair absmax (abs => bit31=0 is the ready
// flag; harness poison 0xAA.. has bit31=1).

#define MROWS 512
#define KDIM  256
#define OCOLS 256
#define NTHR  512
#define RPB   2
#define NBLK  (MROWS / RPB)     // 256
#define NWAVE (NTHR / 64)       // 8
#define E2_GUESS 5
#define E1_GUESS 5

typedef unsigned int u32x4 __attribute__((ext_vector_type(4)));

__device__ __forceinline__ void store_uc(unsigned int* p, unsigned int v) {
    asm volatile("global_store_dword %0, %1, off sc0 sc1"
                 :: "v"((unsigned long long)(uintptr_t)p), "v"(v) : "memory");
}
__device__ __forceinline__ u32x4 load_uc4(const unsigned int* p) {
    u32x4 v;
    asm volatile("global_load_dwordx4 %0, %1, off sc0 sc1\n\t"
                 "s_waitcnt vmcnt(0)"
                 : "=v"(v) : "v"((unsigned long long)(uintptr_t)p) : "memory");
    return v;
}

__device__ __forceinline__ void get_scales(float amax, float dmax, int& e2, int& e1) {
    if (amax == 0.0f) amax = 1.0f;
    if (dmax == 0.0f) dmax = 1.0f;
    float q2 = 32.0f / amax;
    float q1 = 32.0f / dmax;
    int f2 = (q2 >= 1073741824.0f) ? 0x40000000 : (int)floorf(q2);
    int f1 = (q1 >= 1073741824.0f) ? 0x40000000 : (int)floorf(q1);
    if (f2 < 1) f2 = 1;
    if (f1 < 1) f1 = 1;
    e2 = 31 - __clz(f2);
    e1 = 31 - __clz(f1);
}

__device__ __forceinline__ float max4(float4 v) {
    return fmaxf(fmaxf(fabsf(v.x), fabsf(v.y)), fmaxf(fabsf(v.z), fabsf(v.w)));
}

// Integer MAC over K with inline W quantization; folds max|W| into wmax.
__device__ __forceinline__ int mac_loop(const float* __restrict__ W, int o,
                                        const unsigned int* a_sh, float sn1f,
                                        float& wmax) {
    const float4* wrow = (const float4*)(W + (size_t)o * KDIM);
    int sum = 0;
    #pragma unroll 8
    for (int kk = 0; kk < KDIM / 4; ++kk) {
        float4 wv = wrow[kk];
        unsigned int ap = a_sh[kk];
        wmax = fmaxf(wmax, max4(wv));
        float wfv[4] = {wv.x, wv.y, wv.z, wv.w};
        #pragma unroll
        for (int j = 0; j < 4; ++j) {
            int bv = (int)(wfv[j] * sn1f);
            int av = ((int)(ap << (24 - 8 * j))) >> 24;   // sign-extended byte j
            int s  = av * bv;
            sum += (s + ((s >> 31) & 31)) >> 5;           // == sgn*lut[|av|,|bv|]
        }
    }
    return sum;
}

__global__ __launch_bounds__(NTHR)
void k_one(unsigned int* __restrict__ wsp, const float* __restrict__ x,
           const float* __restrict__ W, const float* __restrict__ b,
           float* __restrict__ out) {
    __shared__ unsigned int a_sh[RPB][KDIM / 4];
    __shared__ float sm[2];          // x-rowpair partials from waves 0,1
    __shared__ float smd[NWAVE];     // dmax partials
    __shared__ int s_e[2];

    const int tid  = threadIdx.x;
    const int wave = tid >> 6;
    const int bx   = blockIdx.x;
    const int m0   = bx * RPB;

    const float4* xf = (const float4*)x;
    const int o = tid & (OCOLS - 1);
    const int r = tid >> 8;                  // 0 or 1
    float bo = b[o];

    // ---- speculative quantize of the block's 2 x-rows + rowpair amax ----
    float rm = 0.0f;
    if (tid < RPB * (KDIM / 4)) {            // 128 threads (waves 0,1)
        const int rr = tid >> 6;
        const int oo = tid & 63;
        float4 xv = xf[(size_t)(m0 + rr) * (KDIM / 4) + oo];
        rm = max4(xv);
        const float g2 = (float)(1 << E2_GUESS);
        int a0 = (int)(xv.x * g2) & 0xFF;
        int a1 = (int)(xv.y * g2) & 0xFF;
        int a2 = (int)(xv.z * g2) & 0xFF;
        int a3 = (int)(xv.w * g2) & 0xFF;
        a_sh[rr][oo] = (unsigned int)(a0 | (a1 << 8) | (a2 << 16) | (a3 << 24));
    }
    if (wave < 2) {
        #pragma unroll
        for (int s = 32; s >= 1; s >>= 1)
            rm = fmaxf(rm, __shfl_xor(rm, s, 64));
        if ((tid & 63) == 0) sm[wave] = rm;
    }
    __syncthreads();
    // ---- PUBLISH EARLY: one dword per block, ~1.5us into the kernel ----
    if (tid == 0)
        store_uc(&wsp[bx], __float_as_uint(fmaxf(sm[0], sm[1])));

    // ---- speculative integer MAC; fold exact local dmax of W for free ----
    float wm = 0.0f;
    int sum = mac_loop(W, o, a_sh[r], (float)(1 << E1_GUESS), wm);
    wm = fmaxf(wm, fabsf(bo));               // block reads ALL of b: o covers 0..255
    #pragma unroll
    for (int s = 32; s >= 1; s >>= 1)
        wm = fmaxf(wm, __shfl_xor(wm, s, 64));
    if ((tid & 63) == 0) smd[wave] = wm;
    __syncthreads();

    // ---- CONSUME LATE: poll the 256 rowpair maxes (one dwordx4/lane) ----
    if (wave == 0) {
        u32x4 u;
        bool ok;
        do {
            u = load_uc4(&wsp[4 * tid]);     // lanes 0..63 cover 256 dwords
            ok = __all(((u.x | u.y | u.z | u.w) & 0x80000000u) == 0u);
            if (!ok) __builtin_amdgcn_s_sleep(1);
        } while (!ok);
        float va = fmaxf(fmaxf(__uint_as_float(u.x), __uint_as_float(u.y)),
                         fmaxf(__uint_as_float(u.z), __uint_as_float(u.w)));
        #pragma unroll
        for (int s = 32; s >= 1; s >>= 1)
            va = fmaxf(va, __shfl_xor(va, s, 64));
        if (tid == 0) {
            float vd = smd[0];
            #pragma unroll
            for (int i = 1; i < NWAVE; ++i) vd = fmaxf(vd, smd[i]);
            int e2, e1;
            get_scales(va, vd, e2, e1);      // vd is EXACT local dmax(W,b)
            s_e[0] = e2; s_e[1] = e1;
        }
    }
    __syncthreads();

    const int e2 = s_e[0];
    const int e1 = s_e[1];

    // ---- block-uniform fixup if the guess was wrong (never for bench
    //      data; exact for arbitrary inputs) ----
    if ((e2 != E2_GUESS) | (e1 != E1_GUESS)) {
        if (tid < RPB * (KDIM / 4)) {
            const int rr = tid >> 6;
            const int oo = tid & 63;
            float4 xv = xf[(size_t)(m0 + rr) * (KDIM / 4) + oo];
            const float t2 = (float)(1 << e2);
            int a0 = (int)(xv.x * t2) & 0xFF;
            int a1 = (int)(xv.y * t2) & 0xFF;
            int a2 = (int)(xv.z * t2) & 0xFF;
            int a3 = (int)(xv.w * t2) & 0xFF;
            a_sh[rr][oo] = (unsigned int)(a0 | (a1 << 8) | (a2 << 16) | (a3 << 24));
        }
        __syncthreads();
        float dummy = 0.0f;
        sum = mac_loop(W, o, a_sh[r], (float)(1 << e1), dummy);
    }

    const float sn1f = (float)(1 << e1);
    const int cc = (int)(bo * sn1f);
    const int d  = ((sum + ((sum >> 31) & ((1 << e2) - 1))) >> e2) + cc;
    out[(size_t)(m0 + r) * OCOLS + o] = (float)d * (1.0f / sn1f);
}

extern "C" void kernel_launch(void* const* d_in, const int* in_sizes, int n_in,
                              void* d_out, int out_size, void* d_ws, size_t ws_size,
                              hipStream_t stream) {
    const float* x = (const float*)d_in[0];
    const float* W = (const float*)d_in[1];
    const float* b = (const float*)d_in[2];
    // d_in[3] (lut) unused: lut[i][j] == floor(i*j/32), computed in-ALU.
    float* out = (float*)d_out;
    unsigned int* wsp = (unsigned int*)d_ws;   // 1 KB: per-block x-rowpair maxes

    k_one<<<NBLK, NTHR, 0, stream>>>(wsp, x, W, b, out);
}

// Round 13
// 71.732 us; speedup vs baseline: 1.5234x; 1.0506x over previous
//
#include <hip/hip_runtime.h>
#include <stdint.h>

// SCLinear: out = sc_mat_mac_p(x, W, b, lut, 32)  (forward value of
// lin + stop_grad(p - lin) is exactly p).
// lut[i][j] == floor(i*j/32)  =>  sgn*lut[|a|,|b|] == trunc-toward-zero(a*b/32).
// Exact small-integer arithmetic; no lut memory needed.
//
// R26: COALESCED WAVE-PER-ROW MAC.
// Measured: R13 74.7 / R14 76.8 / R24 75.4 / R15 94.3 / R23 109. All
// MAC kernels land at ~25us regardless of handshake design => the
// handshake was never the bottleneck. Diagnosis: thread-per-W-row maps a
// wave's 64 lanes to 64 DIFFERENT rows (1KB stride) -> 64 cache lines
// per load instruction, 16B used per 128B transaction -> ~14us of L1
// transaction serialization. Fix: transpose the lane mapping.
//   * wave w owns W rows [w*32, w*32+32); per row ONE coalesced load:
//     lane l reads W[o][4l..4l+3] (full 1KB row per instruction).
//   * lane l's x bytes (x[r][4l..4l+3], r=0,1) preloaded in registers
//     (LDS read once); 4 int MACs per lane per row per r; row sum via
//     6-step __shfl_xor butterfly (exact: trunc-div terms are order-free).
//   * lane io keeps row io's r0 sum, lane 32+io keeps r1 -> one coalesced
//     64-output store per wave at the end.
//   * W read ONCE per block (64MB aggregate, half of R24); per-block row
//     rotation (bx) decorrelates cross-block W streams.
//   * dmax: communication-free (fold max|W| into row loop + |b|) [R24].
//   * amax: publish rowpair max early (1 dword/block, sc0sc1), poll all
//     256 after the MAC [R24]. Speculative (e2,e1)=(5,5) + exact
//     block-uniform fixup for arbitrary inputs.
// 256 blocks x 512 threads (1 block/CU; co-residency for the poll safe).
// wsp[bx] = block bx's x-rowpair absmax (bit31==0 is the ready flag;
// harness poison 0xAA.. has bit31=1).

#define MROWS 512
#define KDIM  256
#define OCOLS 256
#define NTHR  512
#define RPB   2
#define NBLK  (MROWS / RPB)     // 256
#define NWAVE (NTHR / 64)       // 8
#define E2_GUESS 5
#define E1_GUESS 5

typedef unsigned int u32x4 __attribute__((ext_vector_type(4)));

__device__ __forceinline__ void store_uc(unsigned int* p, unsigned int v) {
    asm volatile("global_store_dword %0, %1, off sc0 sc1"
                 :: "v"((unsigned long long)(uintptr_t)p), "v"(v) : "memory");
}
__device__ __forceinline__ u32x4 load_uc4(const unsigned int* p) {
    u32x4 v;
    asm volatile("global_load_dwordx4 %0, %1, off sc0 sc1\n\t"
                 "s_waitcnt vmcnt(0)"
                 : "=v"(v) : "v"((unsigned long long)(uintptr_t)p) : "memory");
    return v;
}

__device__ __forceinline__ void get_scales(float amax, float dmax, int& e2, int& e1) {
    if (amax == 0.0f) amax = 1.0f;
    if (dmax == 0.0f) dmax = 1.0f;
    float q2 = 32.0f / amax;
    float q1 = 32.0f / dmax;
    int f2 = (q2 >= 1073741824.0f) ? 0x40000000 : (int)floorf(q2);
    int f1 = (q1 >= 1073741824.0f) ? 0x40000000 : (int)floorf(q1);
    if (f2 < 1) f2 = 1;
    if (f1 < 1) f1 = 1;
    e2 = 31 - __clz(f2);
    e1 = 31 - __clz(f1);
}

__device__ __forceinline__ float max4(float4 v) {
    return fmaxf(fmaxf(fabsf(v.x), fabsf(v.y)), fmaxf(fabsf(v.z), fabsf(v.w)));
}

// Wave-cooperative MAC: this wave covers W rows [obase, obase+32) against
// BOTH x rows (packed bytes ap0/ap1, one uint per lane = 4 K-elements).
// Returns this lane's output (lane io -> row io vs x-row (lane>=32)).
// Folds max|W| over the wave's rows into wmax.
__device__ __forceinline__ int wave_mac(const float* __restrict__ W,
                                        int obase, int lane, int rot,
                                        unsigned int ap0, unsigned int ap1,
                                        float sn1f, float& wmax) {
    int av0[4], av1[4];
    #pragma unroll
    for (int j = 0; j < 4; ++j) {
        av0[j] = ((int)(ap0 << (24 - 8 * j))) >> 24;   // sign-extended byte j
        av1[j] = ((int)(ap1 << (24 - 8 * j))) >> 24;
    }
    const float4* wq = (const float4*)W;
    int res = 0;
    #pragma unroll 4
    for (int i = 0; i < 32; ++i) {
        const int io = (i + rot) & 31;                 // per-block rotation
        const int o  = obase + io;
        float4 wv = wq[(size_t)o * (KDIM / 4) + lane]; // coalesced: 1 row/wave
        wmax = fmaxf(wmax, max4(wv));
        float wf[4] = {wv.x, wv.y, wv.z, wv.w};
        int s0 = 0, s1 = 0;
        #pragma unroll
        for (int j = 0; j < 4; ++j) {
            int bv = (int)(wf[j] * sn1f);
            int p0 = av0[j] * bv;
            int p1 = av1[j] * bv;
            s0 += (p0 + ((p0 >> 31) & 31)) >> 5;       // == sgn*lut[|a|,|b|]
            s1 += (p1 + ((p1 >> 31) & 31)) >> 5;
        }
        #pragma unroll
        for (int sft = 32; sft >= 1; sft >>= 1) {      // exact int row-sum
            s0 += __shfl_xor(s0, sft, 64);
            s1 += __shfl_xor(s1, sft, 64);
        }
        if ((lane & 31) == io) res = (lane >= 32) ? s1 : s0;
    }
    return res;
}

__global__ __launch_bounds__(NTHR)
void k_one(unsigned int* __restrict__ wsp, const float* __restrict__ x,
           const float* __restrict__ W, const float* __restrict__ b,
           float* __restrict__ out) {
    __shared__ unsigned int a_sh[RPB][KDIM / 4];
    __shared__ float sm[2];          // x-rowpair partials from waves 0,1
    __shared__ float smd[NWAVE];     // dmax partials
    __shared__ int s_e[2];

    const int tid  = threadIdx.x;
    const int lane = tid & 63;
    const int w    = tid >> 6;
    const int bx   = blockIdx.x;
    const int m0   = bx * RPB;

    const float4* xf = (const float4*)x;

    // ---- speculative quantize of the block's 2 x-rows + rowpair amax ----
    float rm = 0.0f;
    if (tid < RPB * (KDIM / 4)) {            // 128 threads (waves 0,1)
        const int rr = tid >> 6;
        const int oo = tid & 63;
        float4 xv = xf[(size_t)(m0 + rr) * (KDIM / 4) + oo];
        rm = max4(xv);
        const float g2 = (float)(1 << E2_GUESS);
        int a0 = (int)(xv.x * g2) & 0xFF;
        int a1 = (int)(xv.y * g2) & 0xFF;
        int a2 = (int)(xv.z * g2) & 0xFF;
        int a3 = (int)(xv.w * g2) & 0xFF;
        a_sh[rr][oo] = (unsigned int)(a0 | (a1 << 8) | (a2 << 16) | (a3 << 24));
    }
    if (w < 2) {
        #pragma unroll
        for (int s = 32; s >= 1; s >>= 1)
            rm = fmaxf(rm, __shfl_xor(rm, s, 64));
        if (lane == 0) sm[w] = rm;
    }
    __syncthreads();
    // ---- PUBLISH EARLY: one dword per block ----
    if (tid == 0)
        store_uc(&wsp[bx], __float_as_uint(fmaxf(sm[0], sm[1])));

    // ---- coalesced wave-per-row speculative MAC (+ exact local dmax) ----
    const int obase = w * 32;
    const unsigned int ap0 = a_sh[0][lane];
    const unsigned int ap1 = a_sh[1][lane];
    float wm = 0.0f;
    int res = wave_mac(W, obase, lane, bx, ap0, ap1, (float)(1 << E1_GUESS), wm);

    const float bo = b[obase + (lane & 31)]; // this lane's output column
    wm = fmaxf(wm, fabsf(bo));               // waves jointly cover all of b
    #pragma unroll
    for (int s = 32; s >= 1; s >>= 1)
        wm = fmaxf(wm, __shfl_xor(wm, s, 64));
    if (lane == 0) smd[w] = wm;
    __syncthreads();

    // ---- CONSUME LATE: poll the 256 block maxes (one dwordx4/lane) ----
    if (w == 0) {
        u32x4 u;
        bool ok;
        do {
            u = load_uc4(&wsp[4 * lane]);    // lanes 0..63 cover 256 dwords
            ok = __all(((u.x | u.y | u.z | u.w) & 0x80000000u) == 0u);
            if (!ok) __builtin_amdgcn_s_sleep(1);
        } while (!ok);
        float va = fmaxf(fmaxf(__uint_as_float(u.x), __uint_as_float(u.y)),
                         fmaxf(__uint_as_float(u.z), __uint_as_float(u.w)));
        #pragma unroll
        for (int s = 32; s >= 1; s >>= 1)
            va = fmaxf(va, __shfl_xor(va, s, 64));
        if (lane == 0) {
            float vd = smd[0];
            #pragma unroll
            for (int i = 1; i < NWAVE; ++i) vd = fmaxf(vd, smd[i]);
            int e2, e1;
            get_scales(va, vd, e2, e1);      // vd is EXACT local dmax(W,b)
            s_e[0] = e2; s_e[1] = e1;
        }
    }
    __syncthreads();

    const int e2 = s_e[0];
    const int e1 = s_e[1];

    // ---- block-uniform fixup if the guess was wrong (never for bench
    //      data; exact for arbitrary inputs) ----
    if ((e2 != E2_GUESS) | (e1 != E1_GUESS)) {
        if (tid < RPB * (KDIM / 4)) {
            const int rr = tid >> 6;
            const int oo = tid & 63;
            float4 xv = xf[(size_t)(m0 + rr) * (KDIM / 4) + oo];
            const float t2 = (float)(1 << e2);
            int a0 = (int)(xv.x * t2) & 0xFF;
            int a1 = (int)(xv.y * t2) & 0xFF;
            int a2 = (int)(xv.z * t2) & 0xFF;
            int a3 = (int)(xv.w * t2) & 0xFF;
            a_sh[rr][oo] = (unsigned int)(a0 | (a1 << 8) | (a2 << 16) | (a3 << 24));
        }
        __syncthreads();
        float dummy = 0.0f;
        res = wave_mac(W, obase, lane, bx, a_sh[0][lane], a_sh[1][lane],
                       (float)(1 << e1), dummy);
    }

    const float sn1f = (float)(1 << e1);
    const int cc = (int)(bo * sn1f);
    const int d  = ((res + ((res >> 31) & ((1 << e2) - 1))) >> e2) + cc;
    // lane io -> out[m0+0][obase+io], lane 32+io -> out[m0+1][obase+io]
    out[(size_t)(m0 + (lane >> 5)) * OCOLS + obase + (lane & 31)]
        = (float)d * (1.0f / sn1f);
}

extern "C" void kernel_launch(void* const* d_in, const int* in_sizes, int n_in,
                              void* d_out, int out_size, void* d_ws, size_t ws_size,
                              hipStream_t stream) {
    const float* x = (const float*)d_in[0];
    const float* W = (const float*)d_in[1];
    const float* b = (const float*)d_in[2];
    // d_in[3] (lut) unused: lut[i][j] == floor(i*j/32), computed in-ALU.
    float* out = (float*)d_out;
    unsigned int* wsp = (unsigned int*)d_ws;   // 1 KB: per-block x-rowpair maxes

    k_one<<<NBLK, NTHR, 0, stream>>>(wsp, x, W, b, out);
}

// Round 14
// 71.572 us; speedup vs baseline: 1.5268x; 1.0022x over previous
//
#include <hip/hip_runtime.h>
#include <stdint.h>

// SCLinear: out = sc_mat_mac_p(x, W, b, lut, 32)  (forward value of
// lin + stop_grad(p - lin) is exactly p).
// lut[i][j] == floor(i*j/32)  =>  sgn*lut[|a|,|b|] == trunc-toward-zero(a*b/32).
// Exact small-integer arithmetic; no lut memory needed.
//
// R27: R26 + 2x OCCUPANCY, HALVED PER-WAVE CRITICAL PATH.
// Measured: R26 (coalesced wave-per-row) = 71.7us, best so far. With the
// calibrated split (fill 40.6 + graph residual 10.7) the MAC kernel is
// ~20.4us vs ~6-8us of arithmetic. R26 ran 512thr/block = 2 waves/SIMD;
// each wave's path = 32 row-loads + 32x12 dependent shuffle ops -- too
// little TLP to hide L2 + shuffle-chain latency. This round: 1024
// threads / 16 waves per block, 16 rows per wave. Same total work, same
// W traffic (read once per block), 4 waves/SIMD, half the per-wave
// dependent chain. Everything else verbatim from R26:
//  * wave w owns rows [w*16, w*16+16); per row ONE coalesced 1KB load.
//  * per-row 64-lane __shfl_xor butterfly for the exact int row sums.
//  * dmax: communication-free (fold max|W| into row loop + |b|).
//  * amax: publish rowpair max early (1 dword/block, sc0sc1), poll all
//    256 after the MAC. Speculative (e2,e1)=(5,5) + exact fixup.
// 256 blocks x 1024 threads (1 block/CU). wsp[bx] = block bx's x-rowpair
// absmax (bit31==0 is the ready flag; poison 0xAA.. has bit31=1).

#define MROWS 512
#define KDIM  256
#define OCOLS 256
#define NTHR  1024
#define RPB   2
#define NBLK  (MROWS / RPB)     // 256
#define NWAVE (NTHR / 64)       // 16
#define ROWS_PER_WAVE (OCOLS / NWAVE)   // 16
#define E2_GUESS 5
#define E1_GUESS 5

typedef unsigned int u32x4 __attribute__((ext_vector_type(4)));

__device__ __forceinline__ void store_uc(unsigned int* p, unsigned int v) {
    asm volatile("global_store_dword %0, %1, off sc0 sc1"
                 :: "v"((unsigned long long)(uintptr_t)p), "v"(v) : "memory");
}
__device__ __forceinline__ u32x4 load_uc4(const unsigned int* p) {
    u32x4 v;
    asm volatile("global_load_dwordx4 %0, %1, off sc0 sc1\n\t"
                 "s_waitcnt vmcnt(0)"
                 : "=v"(v) : "v"((unsigned long long)(uintptr_t)p) : "memory");
    return v;
}

__device__ __forceinline__ void get_scales(float amax, float dmax, int& e2, int& e1) {
    if (amax == 0.0f) amax = 1.0f;
    if (dmax == 0.0f) dmax = 1.0f;
    float q2 = 32.0f / amax;
    float q1 = 32.0f / dmax;
    int f2 = (q2 >= 1073741824.0f) ? 0x40000000 : (int)floorf(q2);
    int f1 = (q1 >= 1073741824.0f) ? 0x40000000 : (int)floorf(q1);
    if (f2 < 1) f2 = 1;
    if (f1 < 1) f1 = 1;
    e2 = 31 - __clz(f2);
    e1 = 31 - __clz(f1);
}

__device__ __forceinline__ float max4(float4 v) {
    return fmaxf(fmaxf(fabsf(v.x), fabsf(v.y)), fmaxf(fabsf(v.z), fabsf(v.w)));
}

// Wave-cooperative MAC: this wave covers W rows [obase, obase+16) against
// BOTH x rows (packed bytes ap0/ap1, one uint per lane = 4 K-elements).
// Lane io (io<16) keeps row io's r0 sum; lane 16+io keeps r1.
// Folds max|W| over the wave's rows into wmax.
__device__ __forceinline__ int wave_mac(const float* __restrict__ W,
                                        int obase, int lane, int rot,
                                        unsigned int ap0, unsigned int ap1,
                                        float sn1f, float& wmax) {
    int av0[4], av1[4];
    #pragma unroll
    for (int j = 0; j < 4; ++j) {
        av0[j] = ((int)(ap0 << (24 - 8 * j))) >> 24;   // sign-extended byte j
        av1[j] = ((int)(ap1 << (24 - 8 * j))) >> 24;
    }
    const float4* wq = (const float4*)W;
    int res = 0;
    #pragma unroll 4
    for (int i = 0; i < ROWS_PER_WAVE; ++i) {
        const int io = (i + rot) & (ROWS_PER_WAVE - 1); // per-block rotation
        const int o  = obase + io;
        float4 wv = wq[(size_t)o * (KDIM / 4) + lane];  // coalesced: 1 row/wave
        wmax = fmaxf(wmax, max4(wv));
        float wf[4] = {wv.x, wv.y, wv.z, wv.w};
        int s0 = 0, s1 = 0;
        #pragma unroll
        for (int j = 0; j < 4; ++j) {
            int bv = (int)(wf[j] * sn1f);
            int p0 = av0[j] * bv;
            int p1 = av1[j] * bv;
            s0 += (p0 + ((p0 >> 31) & 31)) >> 5;        // == sgn*lut[|a|,|b|]
            s1 += (p1 + ((p1 >> 31) & 31)) >> 5;
        }
        #pragma unroll
        for (int sft = 32; sft >= 1; sft >>= 1) {       // exact int row-sum
            s0 += __shfl_xor(s0, sft, 64);
            s1 += __shfl_xor(s1, sft, 64);
        }
        if ((lane & (ROWS_PER_WAVE - 1)) == io)
            res = (lane & 16) ? s1 : s0;                // lanes 0-31 useful
    }
    return res;
}

__global__ __launch_bounds__(NTHR)
void k_one(unsigned int* __restrict__ wsp, const float* __restrict__ x,
           const float* __restrict__ W, const float* __restrict__ b,
           float* __restrict__ out) {
    __shared__ unsigned int a_sh[RPB][KDIM / 4];
    __shared__ float sm[2];          // x-rowpair partials from waves 0,1
    __shared__ float smd[NWAVE];     // dmax partials
    __shared__ int s_e[2];

    const int tid  = threadIdx.x;
    const int lane = tid & 63;
    const int w    = tid >> 6;
    const int bx   = blockIdx.x;
    const int m0   = bx * RPB;

    const float4* xf = (const float4*)x;

    // ---- speculative quantize of the block's 2 x-rows + rowpair amax ----
    float rm = 0.0f;
    if (tid < RPB * (KDIM / 4)) {            // 128 threads (waves 0,1)
        const int rr = tid >> 6;
        const int oo = tid & 63;
        float4 xv = xf[(size_t)(m0 + rr) * (KDIM / 4) + oo];
        rm = max4(xv);
        const float g2 = (float)(1 << E2_GUESS);
        int a0 = (int)(xv.x * g2) & 0xFF;
        int a1 = (int)(xv.y * g2) & 0xFF;
        int a2 = (int)(xv.z * g2) & 0xFF;
        int a3 = (int)(xv.w * g2) & 0xFF;
        a_sh[rr][oo] = (unsigned int)(a0 | (a1 << 8) | (a2 << 16) | (a3 << 24));
    }
    if (w < 2) {
        #pragma unroll
        for (int s = 32; s >= 1; s >>= 1)
            rm = fmaxf(rm, __shfl_xor(rm, s, 64));
        if (lane == 0) sm[w] = rm;
    }
    __syncthreads();
    // ---- PUBLISH EARLY: one dword per block ----
    if (tid == 0)
        store_uc(&wsp[bx], __float_as_uint(fmaxf(sm[0], sm[1])));

    // ---- coalesced wave-per-row speculative MAC (+ exact local dmax) ----
    const int obase = w * ROWS_PER_WAVE;
    const unsigned int ap0 = a_sh[0][lane];
    const unsigned int ap1 = a_sh[1][lane];
    float wm = 0.0f;
    int res = wave_mac(W, obase, lane, bx, ap0, ap1, (float)(1 << E1_GUESS), wm);

    const float bo = b[obase + (lane & (ROWS_PER_WAVE - 1))];
    wm = fmaxf(wm, fabsf(bo));               // waves jointly cover all of b
    #pragma unroll
    for (int s = 32; s >= 1; s >>= 1)
        wm = fmaxf(wm, __shfl_xor(wm, s, 64));
    if (lane == 0) smd[w] = wm;
    __syncthreads();

    // ---- CONSUME LATE: poll the 256 block maxes (one dwordx4/lane) ----
    if (w == 0) {
        u32x4 u;
        bool ok;
        do {
            u = load_uc4(&wsp[4 * lane]);    // lanes 0..63 cover 256 dwords
            ok = __all(((u.x | u.y | u.z | u.w) & 0x80000000u) == 0u);
            if (!ok) __builtin_amdgcn_s_sleep(1);
        } while (!ok);
        float va = fmaxf(fmaxf(__uint_as_float(u.x), __uint_as_float(u.y)),
                         fmaxf(__uint_as_float(u.z), __uint_as_float(u.w)));
        #pragma unroll
        for (int s = 32; s >= 1; s >>= 1)
            va = fmaxf(va, __shfl_xor(va, s, 64));
        if (lane == 0) {
            float vd = smd[0];
            #pragma unroll
            for (int i = 1; i < NWAVE; ++i) vd = fmaxf(vd, smd[i]);
            int e2, e1;
            get_scales(va, vd, e2, e1);      // vd is EXACT local dmax(W,b)
            s_e[0] = e2; s_e[1] = e1;
        }
    }
    __syncthreads();

    const int e2 = s_e[0];
    const int e1 = s_e[1];

    // ---- block-uniform fixup if the guess was wrong (never for bench
    //      data; exact for arbitrary inputs) ----
    if ((e2 != E2_GUESS) | (e1 != E1_GUESS)) {
        if (tid < RPB * (KDIM / 4)) {
            const int rr = tid >> 6;
            const int oo = tid & 63;
            float4 xv = xf[(size_t)(m0 + rr) * (KDIM / 4) + oo];
            const float t2 = (float)(1 << e2);
            int a0 = (int)(xv.x * t2) & 0xFF;
            int a1 = (int)(xv.y * t2) & 0xFF;
            int a2 = (int)(xv.z * t2) & 0xFF;
            int a3 = (int)(xv.w * t2) & 0xFF;
            a_sh[rr][oo] = (unsigned int)(a0 | (a1 << 8) | (a2 << 16) | (a3 << 24));
        }
        __syncthreads();
        float dummy = 0.0f;
        res = wave_mac(W, obase, lane, bx, a_sh[0][lane], a_sh[1][lane],
                       (float)(1 << e1), dummy);
    }

    const float sn1f = (float)(1 << e1);
    const int cc = (int)(bo * sn1f);
    const int d  = ((res + ((res >> 31) & ((1 << e2) - 1))) >> e2) + cc;
    // lane io -> out[m0+0][obase+io], lane 16+io -> out[m0+1][obase+io]
    if (lane < 32)
        out[(size_t)(m0 + (lane >> 4)) * OCOLS + obase + (lane & (ROWS_PER_WAVE - 1))]
            = (float)d * (1.0f / sn1f);
}

extern "C" void kernel_launch(void* const* d_in, const int* in_sizes, int n_in,
                              void* d_out, int out_size, void* d_ws, size_t ws_size,
                              hipStream_t stream) {
    const float* x = (const float*)d_in[0];
    const float* W = (const float*)d_in[1];
    const float* b = (const float*)d_in[2];
    // d_in[3] (lut) unused: lut[i][j] == floor(i*j/32), computed in-ALU.
    float* out = (float*)d_out;
    unsigned int* wsp = (unsigned int*)d_ws;   // 1 KB: per-block x-rowpair maxes

    k_one<<<NBLK, NTHR, 0, stream>>>(wsp, x, W, b, out);
}

// Round 15
// 67.193 us; speedup vs baseline: 1.6263x; 1.0652x over previous
//
#include <hip/hip_runtime.h>
#include <stdint.h>

// SCLinear: out = sc_mat_mac_p(x, W, b, lut, 32)  (forward value of
// lin + stop_grad(p - lin) is exactly p).
// lut[i][j] == floor(i*j/32)  =>  sgn*lut[|a|,|b|] == trunc-toward-zero(a*b/32).
// Exact small-integer arithmetic; no lut memory needed.
//
// R28: R27 with the MAC's two biggest per-CU throughput costs cut:
//  (a) FLOAT-TRICK inner loop: trunc(av*bv/32) == (int)((av/32.0f) *
//      truncf(wf*sn1f)). av/32 is dyadic-exact (|av|<=32 by quantization
//      construction: sn2<=32/amax), |av*bv|<=1024 is exactly
//      representable in fp32, and v_cvt_i32_f32 truncates toward zero.
//      Replaces quarter-rate v_mul_lo_u32 + 4-op sign correction with
//      full-rate v_mul_f32 + v_cvt (~32 VALU/row vs ~56).
//  (b) PACKED BUTTERFLY: |row sum| <= 256*32 = 8192 fits int16, so the
//      two x-row sums ride one dword {s1:s0} reduced with v_pk_add_i16:
//      6 shuffles + 6 pk-adds per row instead of 12+12. DS-pipe ops
//      per CU halve.
// Rationale: R26 (2 waves/SIMD) == R27 (4 waves/SIMD) == ~20.3us kernel
// => throughput-bound on per-CU totals, not latency-bound. DS (~5us) and
// VALU (~3us) are the largest modeled per-CU terms -> cut both.
// Everything else verbatim R27: coalesced wave-per-row loads (W read
// once per block), communication-free dmax (fold max|W| into the row
// loop + |b|), publish-early/poll-late amax (sc0sc1), speculative
// (e2,e1)=(5,5) + exact block-uniform fixup.
// 256 blocks x 1024 threads. wsp[bx] = block bx's x-rowpair absmax
// (bit31==0 is the ready flag; harness poison 0xAA.. has bit31=1).

#define MROWS 512
#define KDIM  256
#define OCOLS 256
#define NTHR  1024
#define RPB   2
#define NBLK  (MROWS / RPB)     // 256
#define NWAVE (NTHR / 64)       // 16
#define ROWS_PER_WAVE (OCOLS / NWAVE)   // 16
#define E2_GUESS 5
#define E1_GUESS 5

typedef unsigned int u32x4 __attribute__((ext_vector_type(4)));

__device__ __forceinline__ void store_uc(unsigned int* p, unsigned int v) {
    asm volatile("global_store_dword %0, %1, off sc0 sc1"
                 :: "v"((unsigned long long)(uintptr_t)p), "v"(v) : "memory");
}
__device__ __forceinline__ u32x4 load_uc4(const unsigned int* p) {
    u32x4 v;
    asm volatile("global_load_dwordx4 %0, %1, off sc0 sc1\n\t"
                 "s_waitcnt vmcnt(0)"
                 : "=v"(v) : "v"((unsigned long long)(uintptr_t)p) : "memory");
    return v;
}
__device__ __forceinline__ unsigned int pk_add_i16(unsigned int a, unsigned int b) {
    unsigned int d;
    asm("v_pk_add_i16 %0, %1, %2" : "=v"(d) : "v"(a), "v"(b));
    return d;
}

__device__ __forceinline__ void get_scales(float amax, float dmax, int& e2, int& e1) {
    if (amax == 0.0f) amax = 1.0f;
    if (dmax == 0.0f) dmax = 1.0f;
    float q2 = 32.0f / amax;
    float q1 = 32.0f / dmax;
    int f2 = (q2 >= 1073741824.0f) ? 0x40000000 : (int)floorf(q2);
    int f1 = (q1 >= 1073741824.0f) ? 0x40000000 : (int)floorf(q1);
    if (f2 < 1) f2 = 1;
    if (f1 < 1) f1 = 1;
    e2 = 31 - __clz(f2);
    e1 = 31 - __clz(f1);
}

__device__ __forceinline__ float max4(float4 v) {
    return fmaxf(fmaxf(fabsf(v.x), fabsf(v.y)), fmaxf(fabsf(v.z), fabsf(v.w)));
}

// Wave-cooperative MAC: this wave covers W rows [obase, obase+16) against
// BOTH x rows (packed bytes ap0/ap1, one uint per lane = 4 K-elements).
// Returns a PACKED {s1:hi16, s0:lo16} result: lane io (io<16) holds row
// io's sums. Folds max|W| over the wave's rows into wmax.
__device__ __forceinline__ unsigned int wave_mac(const float* __restrict__ W,
                                                 int obase, int lane, int rot,
                                                 unsigned int ap0, unsigned int ap1,
                                                 float sn1f, float& wmax) {
    float av0f[4], av1f[4];
    #pragma unroll
    for (int j = 0; j < 4; ++j) {
        int a0 = ((int)(ap0 << (24 - 8 * j))) >> 24;   // sign-extended byte j
        int a1 = ((int)(ap1 << (24 - 8 * j))) >> 24;
        av0f[j] = (float)a0 * 0.03125f;                // av/32, dyadic-exact
        av1f[j] = (float)a1 * 0.03125f;
    }
    const float4* wq = (const float4*)W;
    unsigned int res = 0;
    #pragma unroll
    for (int i = 0; i < ROWS_PER_WAVE; ++i) {
        const int io = (i + rot) & (ROWS_PER_WAVE - 1); // per-block rotation
        const int o  = obase + io;
        float4 wv = wq[(size_t)o * (KDIM / 4) + lane];  // coalesced: 1 row/wave
        wmax = fmaxf(wmax, max4(wv));
        float wf[4] = {wv.x, wv.y, wv.z, wv.w};
        int s0 = 0, s1 = 0;
        #pragma unroll
        for (int j = 0; j < 4; ++j) {
            float bvf = truncf(wf[j] * sn1f);          // == (float)bv, exact
            s0 += (int)(av0f[j] * bvf);                // == trunc(av0*bv/32)
            s1 += (int)(av1f[j] * bvf);                // == trunc(av1*bv/32)
        }
        // |per-lane partial| <= 128, |row sum| <= 8192 -> int16-safe.
        unsigned int s = (unsigned int)(s0 & 0xFFFF) | ((unsigned int)s1 << 16);
        #pragma unroll
        for (int sft = 32; sft >= 1; sft >>= 1)        // exact packed row-sum
            s = pk_add_i16(s, (unsigned int)__shfl_xor((int)s, sft, 64));
        if ((lane & (ROWS_PER_WAVE - 1)) == io)
            res = s;
    }
    return res;
}

__global__ __launch_bounds__(NTHR)
void k_one(unsigned int* __restrict__ wsp, const float* __restrict__ x,
           const float* __restrict__ W, const float* __restrict__ b,
           float* __restrict__ out) {
    __shared__ unsigned int a_sh[RPB][KDIM / 4];
    __shared__ float sm[2];          // x-rowpair partials from waves 0,1
    __shared__ float smd[NWAVE];     // dmax partials
    __shared__ int s_e[2];

    const int tid  = threadIdx.x;
    const int lane = tid & 63;
    const int w    = tid >> 6;
    const int bx   = blockIdx.x;
    const int m0   = bx * RPB;

    const float4* xf = (const float4*)x;

    // ---- speculative quantize of the block's 2 x-rows + rowpair amax ----
    float rm = 0.0f;
    if (tid < RPB * (KDIM / 4)) {            // 128 threads (waves 0,1)
        const int rr = tid >> 6;
        const int oo = tid & 63;
        float4 xv = xf[(size_t)(m0 + rr) * (KDIM / 4) + oo];
        rm = max4(xv);
        const float g2 = (float)(1 << E2_GUESS);
        int a0 = (int)(xv.x * g2) & 0xFF;
        int a1 = (int)(xv.y * g2) & 0xFF;
        int a2 = (int)(xv.z * g2) & 0xFF;
        int a3 = (int)(xv.w * g2) & 0xFF;
        a_sh[rr][oo] = (unsigned int)(a0 | (a1 << 8) | (a2 << 16) | (a3 << 24));
    }
    if (w < 2) {
        #pragma unroll
        for (int s = 32; s >= 1; s >>= 1)
            rm = fmaxf(rm, __shfl_xor(rm, s, 64));
        if (lane == 0) sm[w] = rm;
    }
    __syncthreads();
    // ---- PUBLISH EARLY: one dword per block ----
    if (tid == 0)
        store_uc(&wsp[bx], __float_as_uint(fmaxf(sm[0], sm[1])));

    // ---- coalesced wave-per-row speculative MAC (+ exact local dmax) ----
    const int obase = w * ROWS_PER_WAVE;
    const unsigned int ap0 = a_sh[0][lane];
    const unsigned int ap1 = a_sh[1][lane];
    float wm = 0.0f;
    unsigned int res = wave_mac(W, obase, lane, bx, ap0, ap1,
                                (float)(1 << E1_GUESS), wm);

    const float bo = b[obase + (lane & (ROWS_PER_WAVE - 1))];
    wm = fmaxf(wm, fabsf(bo));               // waves jointly cover all of b
    #pragma unroll
    for (int s = 32; s >= 1; s >>= 1)
        wm = fmaxf(wm, __shfl_xor(wm, s, 64));
    if (lane == 0) smd[w] = wm;
    __syncthreads();

    // ---- CONSUME LATE: poll the 256 block maxes (one dwordx4/lane) ----
    if (w == 0) {
        u32x4 u;
        bool ok;
        do {
            u = load_uc4(&wsp[4 * lane]);    // lanes 0..63 cover 256 dwords
            ok = __all(((u.x | u.y | u.z | u.w) & 0x80000000u) == 0u);
            if (!ok) __builtin_amdgcn_s_sleep(1);
        } while (!ok);
        float va = fmaxf(fmaxf(__uint_as_float(u.x), __uint_as_float(u.y)),
                         fmaxf(__uint_as_float(u.z), __uint_as_float(u.w)));
        #pragma unroll
        for (int s = 32; s >= 1; s >>= 1)
            va = fmaxf(va, __shfl_xor(va, s, 64));
        if (lane == 0) {
            float vd = smd[0];
            #pragma unroll
            for (int i = 1; i < NWAVE; ++i) vd = fmaxf(vd, smd[i]);
            int e2, e1;
            get_scales(va, vd, e2, e1);      // vd is EXACT local dmax(W,b)
            s_e[0] = e2; s_e[1] = e1;
        }
    }
    __syncthreads();

    const int e2 = s_e[0];
    const int e1 = s_e[1];

    // ---- block-uniform fixup if the guess was wrong (never for bench
    //      data; exact for arbitrary inputs) ----
    if ((e2 != E2_GUESS) | (e1 != E1_GUESS)) {
        if (tid < RPB * (KDIM / 4)) {
            const int rr = tid >> 6;
            const int oo = tid & 63;
            float4 xv = xf[(size_t)(m0 + rr) * (KDIM / 4) + oo];
            const float t2 = (float)(1 << e2);
            int a0 = (int)(xv.x * t2) & 0xFF;
            int a1 = (int)(xv.y * t2) & 0xFF;
            int a2 = (int)(xv.z * t2) & 0xFF;
            int a3 = (int)(xv.w * t2) & 0xFF;
            a_sh[rr][oo] = (unsigned int)(a0 | (a1 << 8) | (a2 << 16) | (a3 << 24));
        }
        __syncthreads();
        float dummy = 0.0f;
        res = wave_mac(W, obase, lane, bx, a_sh[0][lane], a_sh[1][lane],
                       (float)(1 << e1), dummy);
    }

    // Unpack this lane's sum: lanes 0-15 -> x-row 0 (lo16), 16-31 -> x-row 1.
    const int sum = (lane & 16) ? ((int)res >> 16)
                                : (int)(short)(res & 0xFFFF);

    const float sn1f = (float)(1 << e1);
    const int cc = (int)(bo * sn1f);
    const int d  = ((sum + ((sum >> 31) & ((1 << e2) - 1))) >> e2) + cc;
    // lane io -> out[m0+0][obase+io], lane 16+io -> out[m0+1][obase+io]
    if (lane < 32)
        out[(size_t)(m0 + (lane >> 4)) * OCOLS + obase + (lane & (ROWS_PER_WAVE - 1))]
            = (float)d * (1.0f / sn1f);
}

extern "C" void kernel_launch(void* const* d_in, const int* in_sizes, int n_in,
                              void* d_out, int out_size, void* d_ws, size_t ws_size,
                              hipStream_t stream) {
    const float* x = (const float*)d_in[0];
    const float* W = (const float*)d_in[1];
    const float* b = (const float*)d_in[2];
    // d_in[3] (lut) unused: lut[i][j] == floor(i*j/32), computed in-ALU.
    float* out = (float*)d_out;
    unsigned int* wsp = (unsigned int*)d_ws;   // 1 KB: per-block x-rowpair maxes

    k_one<<<NBLK, NTHR, 0, stream>>>(wsp, x, W, b, out);
}

// Round 16
// 64.787 us; speedup vs baseline: 1.6867x; 1.0371x over previous
//
#include <hip/hip_runtime.h>
#include <stdint.h>

// SCLinear: out = sc_mat_mac_p(x, W, b, lut, 32)  (forward value of
// lin + stop_grad(p - lin) is exactly p).
// lut[i][j] == floor(i*j/32)  =>  sgn*lut[|a|,|b|] == trunc-toward-zero(a*b/32).
// Exact small-integer arithmetic; no lut memory needed.
//
// R29: R28 + 4-ROWS-IN-FLIGHT REDUCTION (DS-pipe cut ~2.7x).
// R28 (67.2us) confirmed the MAC kernel is throughput-bound on per-CU
// VALU+DS totals (float-trick + packed butterfly: -4.4us as predicted).
// Remaining modeled DS cost: 6-step butterfly x 16 rows = 96 steps/wave
// (~3.7us/CU). This round: wave = 4 groups x 16 lanes; group g handles
// row 4c+g in outer iteration c; each lane owns a 16-element k-slice
// (4x float4, same 8-lines/instr coalescing, same load count, same MAC
// count). Row-sum = 4-step within-16-lane packed butterfly shared by 4
// rows -> 16 steps/wave + 8 x-preload ds_reads + 4 final gather shfls.
// Bounds: per-lane partial <= 512, row sum <= 8192 -> int16 packing safe.
// max|W| union over lanes still covers all rows x all k.
// Everything else verbatim R28: coalesced loads (W once per block),
// float-trick exact MAC, communication-free dmax, publish-early/
// poll-late amax (sc0sc1), speculative (5,5) + exact fixup.
// 256 blocks x 1024 threads. wsp[bx] = block bx's x-rowpair absmax
// (bit31==0 ready flag; harness poison 0xAA.. has bit31=1).

#define MROWS 512
#define KDIM  256
#define OCOLS 256
#define NTHR  1024
#define RPB   2
#define NBLK  (MROWS / RPB)     // 256
#define NWAVE (NTHR / 64)       // 16
#define ROWS_PER_WAVE (OCOLS / NWAVE)   // 16
#define E2_GUESS 5
#define E1_GUESS 5

typedef unsigned int u32x4 __attribute__((ext_vector_type(4)));

__device__ __forceinline__ void store_uc(unsigned int* p, unsigned int v) {
    asm volatile("global_store_dword %0, %1, off sc0 sc1"
                 :: "v"((unsigned long long)(uintptr_t)p), "v"(v) : "memory");
}
__device__ __forceinline__ u32x4 load_uc4(const unsigned int* p) {
    u32x4 v;
    asm volatile("global_load_dwordx4 %0, %1, off sc0 sc1\n\t"
                 "s_waitcnt vmcnt(0)"
                 : "=v"(v) : "v"((unsigned long long)(uintptr_t)p) : "memory");
    return v;
}
__device__ __forceinline__ unsigned int pk_add_i16(unsigned int a, unsigned int b) {
    unsigned int d;
    asm("v_pk_add_i16 %0, %1, %2" : "=v"(d) : "v"(a), "v"(b));
    return d;
}

__device__ __forceinline__ void get_scales(float amax, float dmax, int& e2, int& e1) {
    if (amax == 0.0f) amax = 1.0f;
    if (dmax == 0.0f) dmax = 1.0f;
    float q2 = 32.0f / amax;
    float q1 = 32.0f / dmax;
    int f2 = (q2 >= 1073741824.0f) ? 0x40000000 : (int)floorf(q2);
    int f1 = (q1 >= 1073741824.0f) ? 0x40000000 : (int)floorf(q1);
    if (f2 < 1) f2 = 1;
    if (f1 < 1) f1 = 1;
    e2 = 31 - __clz(f2);
    e1 = 31 - __clz(f1);
}

__device__ __forceinline__ float max4(float4 v) {
    return fmaxf(fmaxf(fabsf(v.x), fabsf(v.y)), fmaxf(fabsf(v.z), fabsf(v.w)));
}

// Wave-cooperative MAC, 4 rows in flight. Lane: t=lane&15 (k-slice),
// g=lane>>4 (row group). Outer iter c: group g computes row
// obase + 4*((c+rot)&3) + g over the lane's 16 k-elements; 4-step packed
// butterfly within the 16-lane group reduces all 4 rows at once.
// Returns packed {s1:hi,s0:lo} for this lane's target row obase+(lane&15).
// Folds max|W| over everything this lane loaded into wmax.
__device__ __forceinline__ unsigned int wave_mac(const float* __restrict__ W,
                                                 int obase, int lane, int rot,
                                                 u32x4 xp0, u32x4 xp1,
                                                 float sn1f, float& wmax) {
    // av/32 floats for the lane's 16 k-elements x 2 x-rows (dyadic-exact).
    float a0f[4][4], a1f[4][4];
    unsigned int xw0[4] = {xp0.x, xp0.y, xp0.z, xp0.w};
    unsigned int xw1[4] = {xp1.x, xp1.y, xp1.z, xp1.w};
    #pragma unroll
    for (int c2 = 0; c2 < 4; ++c2) {
        #pragma unroll
        for (int j = 0; j < 4; ++j) {
            a0f[c2][j] = (float)(((int)(xw0[c2] << (24 - 8 * j))) >> 24) * 0.03125f;
            a1f[c2][j] = (float)(((int)(xw1[c2] << (24 - 8 * j))) >> 24) * 0.03125f;
        }
    }
    const float4* wq = (const float4*)W;
    const int t = lane & 15;
    const int g = lane >> 4;
    unsigned int res0 = 0, res1 = 0, res2 = 0, res3 = 0;
    #pragma unroll
    for (int c = 0; c < 4; ++c) {
        const int cc = (c + rot) & 3;                 // wave-uniform
        const int o  = obase + 4 * cc + g;
        float4 wv[4];
        #pragma unroll
        for (int c2 = 0; c2 < 4; ++c2)
            wv[c2] = wq[(size_t)o * (KDIM / 4) + t + 16 * c2];
        int s0 = 0, s1 = 0;
        #pragma unroll
        for (int c2 = 0; c2 < 4; ++c2) {
            wmax = fmaxf(wmax, max4(wv[c2]));
            float wf[4] = {wv[c2].x, wv[c2].y, wv[c2].z, wv[c2].w};
            #pragma unroll
            for (int j = 0; j < 4; ++j) {
                float bvf = truncf(wf[j] * sn1f);     // == (float)bv, exact
                s0 += (int)(a0f[c2][j] * bvf);        // == trunc(av0*bv/32)
                s1 += (int)(a1f[c2][j] * bvf);
            }
        }
        // |per-lane partial| <= 512, |row sum| <= 8192 -> int16-safe.
        unsigned int s = (unsigned int)(s0 & 0xFFFF) | ((unsigned int)s1 << 16);
        #pragma unroll
        for (int sft = 8; sft >= 1; sft >>= 1)        // within-16 butterfly
            s = pk_add_i16(s, (unsigned int)__shfl_xor((int)s, sft, 64));
        if (c == 0) res0 = s; else if (c == 1) res1 = s;
        else if (c == 2) res2 = s; else res3 = s;
    }
    // Gather: lane's target row r=lane&15 was produced by group r&3 in the
    // iteration c with (c+rot)&3 == r>>2.
    const int r   = lane & 15;
    const int src = ((r & 3) << 4) + t;               // any lane of group r&3
    unsigned int v0 = (unsigned int)__shfl((int)res0, src, 64);
    unsigned int v1 = (unsigned int)__shfl((int)res1, src, 64);
    unsigned int v2 = (unsigned int)__shfl((int)res2, src, 64);
    unsigned int v3 = (unsigned int)__shfl((int)res3, src, 64);
    const int csel = ((r >> 2) - rot) & 3;
    return (csel == 0) ? v0 : (csel == 1) ? v1 : (csel == 2) ? v2 : v3;
}

__global__ __launch_bounds__(NTHR)
void k_one(unsigned int* __restrict__ wsp, const float* __restrict__ x,
           const float* __restrict__ W, const float* __restrict__ b,
           float* __restrict__ out) {
    __shared__ unsigned int a_sh[RPB][KDIM / 4];
    __shared__ float sm[2];          // x-rowpair partials from waves 0,1
    __shared__ float smd[NWAVE];     // dmax partials
    __shared__ int s_e[2];

    const int tid  = threadIdx.x;
    const int lane = tid & 63;
    const int w    = tid >> 6;
    const int bx   = blockIdx.x;
    const int m0   = bx * RPB;
    const int rot  = bx & 3;

    const float4* xf = (const float4*)x;

    // ---- speculative quantize of the block's 2 x-rows + rowpair amax ----
    float rm = 0.0f;
    if (tid < RPB * (KDIM / 4)) {            // 128 threads (waves 0,1)
        const int rr = tid >> 6;
        const int oo = tid & 63;
        float4 xv = xf[(size_t)(m0 + rr) * (KDIM / 4) + oo];
        rm = max4(xv);
        const float g2 = (float)(1 << E2_GUESS);
        int a0 = (int)(xv.x * g2) & 0xFF;
        int a1 = (int)(xv.y * g2) & 0xFF;
        int a2 = (int)(xv.z * g2) & 0xFF;
        int a3 = (int)(xv.w * g2) & 0xFF;
        a_sh[rr][oo] = (unsigned int)(a0 | (a1 << 8) | (a2 << 16) | (a3 << 24));
    }
    if (w < 2) {
        #pragma unroll
        for (int s = 32; s >= 1; s >>= 1)
            rm = fmaxf(rm, __shfl_xor(rm, s, 64));
        if (lane == 0) sm[w] = rm;
    }
    __syncthreads();
    // ---- PUBLISH EARLY: one dword per block ----
    if (tid == 0)
        store_uc(&wsp[bx], __float_as_uint(fmaxf(sm[0], sm[1])));

    // ---- x-slice preload (8 ds_reads) + coalesced 4-row-group MAC ----
    const int obase = w * ROWS_PER_WAVE;
    const int t = lane & 15;
    u32x4 xp0, xp1;
    xp0.x = a_sh[0][t];      xp0.y = a_sh[0][t + 16];
    xp0.z = a_sh[0][t + 32]; xp0.w = a_sh[0][t + 48];
    xp1.x = a_sh[1][t];      xp1.y = a_sh[1][t + 16];
    xp1.z = a_sh[1][t + 32]; xp1.w = a_sh[1][t + 48];
    float wm = 0.0f;
    unsigned int res = wave_mac(W, obase, lane, rot, xp0, xp1,
                                (float)(1 << E1_GUESS), wm);

    const float bo = b[obase + (lane & 15)];
    wm = fmaxf(wm, fabsf(bo));               // waves jointly cover all of b
    #pragma unroll
    for (int s = 32; s >= 1; s >>= 1)
        wm = fmaxf(wm, __shfl_xor(wm, s, 64));
    if (lane == 0) smd[w] = wm;
    __syncthreads();

    // ---- CONSUME LATE: poll the 256 block maxes (one dwordx4/lane) ----
    if (w == 0) {
        u32x4 u;
        bool ok;
        do {
            u = load_uc4(&wsp[4 * lane]);    // lanes 0..63 cover 256 dwords
            ok = __all(((u.x | u.y | u.z | u.w) & 0x80000000u) == 0u);
            if (!ok) __builtin_amdgcn_s_sleep(1);
        } while (!ok);
        float va = fmaxf(fmaxf(__uint_as_float(u.x), __uint_as_float(u.y)),
                         fmaxf(__uint_as_float(u.z), __uint_as_float(u.w)));
        #pragma unroll
        for (int s = 32; s >= 1; s >>= 1)
            va = fmaxf(va, __shfl_xor(va, s, 64));
        if (lane == 0) {
            float vd = smd[0];
            #pragma unroll
            for (int i = 1; i < NWAVE; ++i) vd = fmaxf(vd, smd[i]);
            int e2, e1;
            get_scales(va, vd, e2, e1);      // vd is EXACT local dmax(W,b)
            s_e[0] = e2; s_e[1] = e1;
        }
    }
    __syncthreads();

    const int e2 = s_e[0];
    const int e1 = s_e[1];

    // ---- block-uniform fixup if the guess was wrong (never for bench
    //      data; exact for arbitrary inputs) ----
    if ((e2 != E2_GUESS) | (e1 != E1_GUESS)) {
        if (tid < RPB * (KDIM / 4)) {
            const int rr = tid >> 6;
            const int oo = tid & 63;
            float4 xv = xf[(size_t)(m0 + rr) * (KDIM / 4) + oo];
            const float t2 = (float)(1 << e2);
            int a0 = (int)(xv.x * t2) & 0xFF;
            int a1 = (int)(xv.y * t2) & 0xFF;
            int a2 = (int)(xv.z * t2) & 0xFF;
            int a3 = (int)(xv.w * t2) & 0xFF;
            a_sh[rr][oo] = (unsigned int)(a0 | (a1 << 8) | (a2 << 16) | (a3 << 24));
        }
        __syncthreads();
        u32x4 yp0, yp1;
        yp0.x = a_sh[0][t];      yp0.y = a_sh[0][t + 16];
        yp0.z = a_sh[0][t + 32]; yp0.w = a_sh[0][t + 48];
        yp1.x = a_sh[1][t];      yp1.y = a_sh[1][t + 16];
        yp1.z = a_sh[1][t + 32]; yp1.w = a_sh[1][t + 48];
        float dummy = 0.0f;
        res = wave_mac(W, obase, lane, rot, yp0, yp1, (float)(1 << e1), dummy);
    }

    // ---- epilogue: lanes 0..15 store both x-rows for their column ----
    if (lane < 16) {
        const int s0 = (int)(short)(res & 0xFFFF);
        const int s1 = (int)res >> 16;
        const float sn1f = (float)(1 << e1);
        const int cc = (int)(bo * sn1f);
        const int mask = (1 << e2) - 1;
        const int d0 = ((s0 + ((s0 >> 31) & mask)) >> e2) + cc;
        const int d1 = ((s1 + ((s1 >> 31) & mask)) >> e2) + cc;
        const float inv = 1.0f / sn1f;
        out[(size_t)m0 * OCOLS + obase + lane]       = (float)d0 * inv;
        out[(size_t)(m0 + 1) * OCOLS + obase + lane] = (float)d1 * inv;
    }
}

extern "C" void kernel_launch(void* const* d_in, const int* in_sizes, int n_in,
                              void* d_out, int out_size, void* d_ws, size_t ws_size,
                              hipStream_t stream) {
    const float* x = (const float*)d_in[0];
    const float* W = (const float*)d_in[1];
    const float* b = (const float*)d_in[2];
    // d_in[3] (lut) unused: lut[i][j] == floor(i*j/32), computed in-ALU.
    float* out = (float*)d_out;
    unsigned int* wsp = (unsigned int*)d_ws;   // 1 KB: per-block x-rowpair maxes

    k_one<<<NBLK, NTHR, 0, stream>>>(wsp, x, W, b, out);
}